// Round 1
// baseline (2319.136 us; speedup 1.0000x reference)
//
#include <hip/hip_runtime.h>
#include <hip/hip_bf16.h>
#include <stdint.h>

#define DECAY 0.951229424500714f

// problem sizes (fixed by setup_inputs)
#define BATCH 16
#define TSTEPS 16

// ws layout (float element offsets unless noted)
#define OFF_VM0 0                       // [16][32][64][64] = 2M floats
#define OFF_S0  2097152                 // [16][32][64][64]
#define OFF_VM1 4194304                 // [16][64][64][64] = 4M floats
#define OFF_S1  8388608                 // [16][64][64][64]
#define ZERO_BYTES (12582912u * 4u)     // vm0,s0,vm1,s1 must start at 0
#define OFF_FLAT_BYTES (12582912u * 4u) // bf16 ushort [256][65536] (m = t*16+b)
#define OFF_PART_BYTES (OFF_FLAT_BYTES + 256u*65536u*2u) // fp32 [KSPLIT][256][512]
#define KSPLIT 32
#define KCHUNK (65536 / KSPLIT)         // 2048

// ---------------- conv0 (2->32, 3x3, pad 1) + LIF0 ----------------
__global__ __launch_bounds__(256) void conv0_lif(const float* __restrict__ in,
                                                 const float* __restrict__ W0,
                                                 float* __restrict__ ws, int t) {
    int pix = blockIdx.x * 256 + threadIdx.x;   // 0..4095
    int oc  = blockIdx.y;                        // 0..31
    int b   = blockIdx.z;                        // 0..15
    int y = pix >> 6, x = pix & 63;
    const float* xin = in + (size_t)((b * TSTEPS + t) * 2) * 4096;
    float acc = 0.f;
#pragma unroll
    for (int ic = 0; ic < 2; ++ic) {
        const float* xc = xin + ic * 4096;
        const float* wp = W0 + (oc * 2 + ic) * 9;
#pragma unroll
        for (int dy = 0; dy < 3; ++dy) {
            int sy = y + dy - 1;
            bool vy = (unsigned)sy < 64u;
#pragma unroll
            for (int dx = 0; dx < 3; ++dx) {
                int sx = x + dx - 1;
                bool v = vy && ((unsigned)sx < 64u);
                float val = v ? xc[sy * 64 + sx] : 0.f;
                val = fminf(fmaxf(val, 0.f), 1.f);    // clip(x,0,1)
                acc = fmaf(val, wp[dy * 3 + dx], acc);
            }
        }
    }
    int idx = (b * 32 + oc) * 4096 + pix;
    float vm = ws[OFF_VM0 + idx];
    float sp = ws[OFF_S0 + idx];
    vm = vm * DECAY * (1.f - sp) + acc;
    ws[OFF_VM0 + idx] = vm;
    ws[OFF_S0 + idx] = (vm > 0.5f) ? 1.f : 0.f;
}

// ---------------- conv1 (32->64, 3x3, pad 1) + LIF1 ----------------
// block (64,4): x = full row, 4 rows. Each thread: 1 pixel x 16 oc.
__global__ __launch_bounds__(256) void conv1_lif(const float* __restrict__ W1,
                                                 float* __restrict__ ws) {
    int x = threadIdx.x;
    int y = blockIdx.y * 4 + threadIdx.y;
    int ocg = blockIdx.x;       // 0..3 (16 oc each)
    int b = blockIdx.z;
    const float* s0 = ws + OFF_S0 + (size_t)b * 32 * 4096;
    float acc[16];
#pragma unroll
    for (int i = 0; i < 16; ++i) acc[i] = 0.f;

    for (int ic = 0; ic < 32; ++ic) {
        const float* sc = s0 + ic * 4096;
        float v[9];
#pragma unroll
        for (int dy = 0; dy < 3; ++dy) {
            int sy = y + dy - 1;
            bool vy = (unsigned)sy < 64u;
#pragma unroll
            for (int dx = 0; dx < 3; ++dx) {
                int sx = x + dx - 1;
                v[dy * 3 + dx] = (vy && (unsigned)sx < 64u) ? sc[sy * 64 + sx] : 0.f;
            }
        }
#pragma unroll
        for (int u = 0; u < 16; ++u) {
            const float* wp = W1 + ((ocg * 16 + u) * 32 + ic) * 9;  // uniform -> s_load
#pragma unroll
            for (int k = 0; k < 9; ++k) acc[u] = fmaf(v[k], wp[k], acc[u]);
        }
    }
    int pixbase = y * 64 + x;
#pragma unroll
    for (int u = 0; u < 16; ++u) {
        int idx = (b * 64 + ocg * 16 + u) * 4096 + pixbase;
        float vm = ws[OFF_VM1 + idx];
        float sp = ws[OFF_S1 + idx];
        vm = vm * DECAY * (1.f - sp) + acc[u];
        ws[OFF_VM1 + idx] = vm;
        ws[OFF_S1 + idx] = (vm > 0.5f) ? 1.f : 0.f;
    }
}

// ---------------- maxpool 2x2 on s1 -> flat_all[t] (bf16, exact 0/1) ----------------
__global__ __launch_bounds__(256) void pool_pack(float* __restrict__ ws, int t) {
    int k = blockIdx.x * 256 + threadIdx.x;   // 0..65535 = c*1024 + y2*32 + x2
    int b = blockIdx.y;
    int c = k >> 10, r = (k >> 5) & 31, cc = k & 31;
    const float* s1 = ws + OFF_S1 + (((size_t)(b * 64 + c) * 64 + r * 2) * 64 + cc * 2);
    float m = fmaxf(fmaxf(s1[0], s1[1]), fmaxf(s1[64], s1[65]));
    unsigned short* flat = (unsigned short*)((char*)ws + OFF_FLAT_BYTES);
    flat[(size_t)(t * 16 + b) * 65536 + k] = (m > 0.5f) ? (unsigned short)0x3F80 : (unsigned short)0;
}

// ---------------- dense0 batched over all t: [256 x 65536] @ D0^T -> partials ----------------
// grid (4 mb, 8 nb, KSPLIT kc), block 256. Tile 64x64, k-chunk 2048. Deterministic split-K.
__global__ __launch_bounds__(256) void dense0_gemm(const float* __restrict__ D0,
                                                   float* __restrict__ ws) {
    __shared__ float As[32][68];
    __shared__ float Bs[32][68];
    int tid = threadIdx.x;
    int mb = blockIdx.x, nb = blockIdx.y, kc = blockIdx.z;
    const unsigned short* flat = (const unsigned short*)((const char*)ws + OFF_FLAT_BYTES);
    float acc[4][4] = {};
    int tx = tid & 15, ty = tid >> 4;
    int rs = tid >> 2;            // staging row 0..63
    int ks = (tid & 3) * 8;       // staging k offset 0/8/16/24
    const unsigned short* aptr = flat + (size_t)(mb * 64 + rs) * 65536 + kc * KCHUNK + ks;
    const float* bptr = D0 + (size_t)(nb * 64 + rs) * 65536 + kc * KCHUNK + ks;

    for (int k0 = 0; k0 < KCHUNK; k0 += 32) {
        uint4 av = *(const uint4*)(aptr + k0);
        float4 b0 = *(const float4*)(bptr + k0);
        float4 b1 = *(const float4*)(bptr + k0 + 4);
        unsigned aw[4] = {av.x, av.y, av.z, av.w};
#pragma unroll
        for (int i = 0; i < 4; ++i) {
            As[ks + 2 * i][rs]     = __uint_as_float(aw[i] << 16);
            As[ks + 2 * i + 1][rs] = __uint_as_float(aw[i] & 0xFFFF0000u);
        }
        Bs[ks + 0][rs] = b0.x; Bs[ks + 1][rs] = b0.y; Bs[ks + 2][rs] = b0.z; Bs[ks + 3][rs] = b0.w;
        Bs[ks + 4][rs] = b1.x; Bs[ks + 5][rs] = b1.y; Bs[ks + 6][rs] = b1.z; Bs[ks + 7][rs] = b1.w;
        __syncthreads();
#pragma unroll
        for (int kk = 0; kk < 32; ++kk) {
            float4 a = *(const float4*)&As[kk][ty * 4];
            float4 bv = *(const float4*)&Bs[kk][tx * 4];
            acc[0][0] = fmaf(a.x, bv.x, acc[0][0]); acc[0][1] = fmaf(a.x, bv.y, acc[0][1]);
            acc[0][2] = fmaf(a.x, bv.z, acc[0][2]); acc[0][3] = fmaf(a.x, bv.w, acc[0][3]);
            acc[1][0] = fmaf(a.y, bv.x, acc[1][0]); acc[1][1] = fmaf(a.y, bv.y, acc[1][1]);
            acc[1][2] = fmaf(a.y, bv.z, acc[1][2]); acc[1][3] = fmaf(a.y, bv.w, acc[1][3]);
            acc[2][0] = fmaf(a.z, bv.x, acc[2][0]); acc[2][1] = fmaf(a.z, bv.y, acc[2][1]);
            acc[2][2] = fmaf(a.z, bv.z, acc[2][2]); acc[2][3] = fmaf(a.z, bv.w, acc[2][3]);
            acc[3][0] = fmaf(a.w, bv.x, acc[3][0]); acc[3][1] = fmaf(a.w, bv.y, acc[3][1]);
            acc[3][2] = fmaf(a.w, bv.z, acc[3][2]); acc[3][3] = fmaf(a.w, bv.w, acc[3][3]);
        }
        __syncthreads();
    }
    float* part = (float*)((char*)ws + OFF_PART_BYTES);
#pragma unroll
    for (int i = 0; i < 4; ++i) {
        int m = mb * 64 + ty * 4 + i;
        float* row = part + ((size_t)kc * 256 + m) * 512 + nb * 64 + tx * 4;
        *(float4*)row = make_float4(acc[i][0], acc[i][1], acc[i][2], acc[i][3]);
    }
}

// ---------------- tail: LIF2 + dense1 + LIF3 + acc over all t (single block) ----------------
__global__ __launch_bounds__(512) void tail_kernel(const float* __restrict__ D1,
                                                   float* __restrict__ out,
                                                   const float* __restrict__ ws_ro) {
    __shared__ float s2l[16][512];
    __shared__ float d1l[11 * 512];
    __shared__ float pb[2][176];
    int tid = threadIdx.x;
    for (int i = tid; i < 11 * 512; i += 512) d1l[i] = D1[i];
    const float* part = (const float*)((const char*)ws_ro + OFF_PART_BYTES);

    float vm2[16];
#pragma unroll
    for (int i = 0; i < 16; ++i) vm2[i] = 0.f;
    unsigned s2mask = 0;
    float vm3 = 0.f, s3 = 0.f, accv = 0.f;
    int rb = tid / 11, ro = tid % 11;   // valid when tid < 176
    __syncthreads();

    for (int t = 0; t < TSTEPS; ++t) {
        // phase A: LIF2 — thread tid owns column j=tid for all 16 batches
        {
            int j = tid;
#pragma unroll
            for (int b = 0; b < 16; ++b) {
                float I = 0.f;
                for (int c = 0; c < KSPLIT; ++c)
                    I += part[((size_t)c * 256 + t * 16 + b) * 512 + j];
                float sp = ((s2mask >> b) & 1u) ? 1.f : 0.f;
                float vm = vm2[b] * DECAY * (1.f - sp) + I;
                vm2[b] = vm;
                unsigned sb = (vm > 0.5f) ? 1u : 0u;
                s2mask = (s2mask & ~(1u << b)) | (sb << b);
                s2l[b][j] = (float)sb;
            }
        }
        __syncthreads();
        // phase B: dense1 partials (2 k-halves x 176 outputs)
        if (tid < 352) {
            int g = tid / 176, r = tid % 176;
            int b = r / 11, o = r % 11;
            float p = 0.f;
            int kbase = g * 256;
            for (int k = 0; k < 256; ++k)
                p = fmaf(s2l[b][kbase + k], d1l[o * 512 + kbase + k], p);
            pb[g][r] = p;
        }
        __syncthreads();
        // phase C: LIF3 + acc (concurrent with nothing touching pb until next barrier pair)
        if (tid < 176) {
            float I3 = pb[0][tid] + pb[1][tid];
            float vm = vm3 * DECAY * (1.f - s3) + I3;
            vm3 = vm;
            s3 = (vm > 0.5f) ? 1.f : 0.f;
            accv += s3;
        }
        __syncthreads();
    }
    if (tid < 176) out[rb * 11 + ro] = accv * (1.f / 16.f);
}

extern "C" void kernel_launch(void* const* d_in, const int* in_sizes, int n_in,
                              void* d_out, int out_size, void* d_ws, size_t ws_size,
                              hipStream_t stream) {
    (void)in_sizes; (void)n_in; (void)out_size; (void)ws_size;
    const float* in = (const float*)d_in[0];
    const float* W0 = (const float*)d_in[1];
    const float* W1 = (const float*)d_in[2];
    const float* D0 = (const float*)d_in[3];
    const float* D1 = (const float*)d_in[4];
    float* ws = (float*)d_ws;
    float* out = (float*)d_out;

    // zero the persistent LIF state (vm0,s0,vm1,s1) — ws is poisoned before every call
    hipMemsetAsync(d_ws, 0, ZERO_BYTES, stream);

    for (int t = 0; t < TSTEPS; ++t) {
        conv0_lif<<<dim3(16, 32, 16), 256, 0, stream>>>(in, W0, ws, t);
        conv1_lif<<<dim3(4, 16, 16), dim3(64, 4, 1), 0, stream>>>(W1, ws);
        pool_pack<<<dim3(256, 16), 256, 0, stream>>>(ws, t);
    }
    dense0_gemm<<<dim3(4, 8, KSPLIT), 256, 0, stream>>>(D0, ws);
    tail_kernel<<<1, 512, 0, stream>>>(D1, out, ws);
}

// Round 2
// 2096.710 us; speedup vs baseline: 1.1061x; 1.1061x over previous
//
#include <hip/hip_runtime.h>
#include <hip/hip_bf16.h>
#include <stdint.h>

#define DECAY 0.951229424500714f

// problem sizes (fixed by setup_inputs)
#define BATCH 16
#define TSTEPS 16

// ws layout (float element offsets unless noted)
#define OFF_VM0 0                       // [16][32][64][64] = 2M floats
#define OFF_S0  2097152                 // [16][32][64][64]
#define OFF_VM1 4194304                 // [16][64][64][64] = 4M floats
#define OFF_S1  8388608                 // [16][64][64][64]
#define ZERO_BYTES (12582912u * 4u)     // vm0,s0,vm1,s1 must start at 0
#define OFF_FLAT_BYTES (12582912u * 4u) // bf16 ushort [256][65536] (m = t*16+b)
// After the conv loop, vm0/s0/vm1/s1 are dead -> overlay GEMM partials there.
#define KSPLIT 64
#define KCHUNK (65536 / KSPLIT)         // 1024
#define OFF_PART_BYTES 0u               // fp32 [KSPLIT][256][512] = 33.5 MB (overlays vm0/s0/vm1)
#define OFF_I_BYTES (64u * 256u * 512u * 4u)  // fp32 [256][512] at byte 33554432 (inside dead vm1)

typedef __attribute__((ext_vector_type(8))) short short8;
typedef __attribute__((ext_vector_type(4))) float floatx4;

__device__ inline unsigned short f2bf_rne(float f) {
    unsigned u = __float_as_uint(f);
    unsigned r = (u + 0x7FFFu + ((u >> 16) & 1u)) >> 16;
    return (unsigned short)r;
}
__device__ inline float bf2f(unsigned short h) {
    return __uint_as_float(((unsigned)h) << 16);
}

// ---------------- conv0 (2->32, 3x3, pad 1) + LIF0 ----------------
__global__ __launch_bounds__(256) void conv0_lif(const float* __restrict__ in,
                                                 const float* __restrict__ W0,
                                                 float* __restrict__ ws, int t) {
    int pix = blockIdx.x * 256 + threadIdx.x;   // 0..4095
    int oc  = blockIdx.y;                        // 0..31
    int b   = blockIdx.z;                        // 0..15
    int y = pix >> 6, x = pix & 63;
    const float* xin = in + (size_t)((b * TSTEPS + t) * 2) * 4096;
    float acc = 0.f;
#pragma unroll
    for (int ic = 0; ic < 2; ++ic) {
        const float* xc = xin + ic * 4096;
        const float* wp = W0 + (oc * 2 + ic) * 9;
#pragma unroll
        for (int dy = 0; dy < 3; ++dy) {
            int sy = y + dy - 1;
            bool vy = (unsigned)sy < 64u;
#pragma unroll
            for (int dx = 0; dx < 3; ++dx) {
                int sx = x + dx - 1;
                bool v = vy && ((unsigned)sx < 64u);
                float val = v ? xc[sy * 64 + sx] : 0.f;
                val = fminf(fmaxf(val, 0.f), 1.f);    // clip(x,0,1)
                acc = fmaf(val, wp[dy * 3 + dx], acc);
            }
        }
    }
    int idx = (b * 32 + oc) * 4096 + pix;
    float vm = ws[OFF_VM0 + idx];
    float sp = ws[OFF_S0 + idx];
    vm = vm * DECAY * (1.f - sp) + acc;
    ws[OFF_VM0 + idx] = vm;
    ws[OFF_S0 + idx] = (vm > 0.5f) ? 1.f : 0.f;
}

// ---------------- conv1 (32->64, 3x3, pad 1) + LIF1 ----------------
__global__ __launch_bounds__(256) void conv1_lif(const float* __restrict__ W1,
                                                 float* __restrict__ ws) {
    int x = threadIdx.x;
    int y = blockIdx.y * 4 + threadIdx.y;
    int ocg = blockIdx.x;       // 0..3 (16 oc each)
    int b = blockIdx.z;
    const float* s0 = ws + OFF_S0 + (size_t)b * 32 * 4096;
    float acc[16];
#pragma unroll
    for (int i = 0; i < 16; ++i) acc[i] = 0.f;

    for (int ic = 0; ic < 32; ++ic) {
        const float* sc = s0 + ic * 4096;
        float v[9];
#pragma unroll
        for (int dy = 0; dy < 3; ++dy) {
            int sy = y + dy - 1;
            bool vy = (unsigned)sy < 64u;
#pragma unroll
            for (int dx = 0; dx < 3; ++dx) {
                int sx = x + dx - 1;
                v[dy * 3 + dx] = (vy && (unsigned)sx < 64u) ? sc[sy * 64 + sx] : 0.f;
            }
        }
#pragma unroll
        for (int u = 0; u < 16; ++u) {
            const float* wp = W1 + ((ocg * 16 + u) * 32 + ic) * 9;  // uniform -> s_load
#pragma unroll
            for (int k = 0; k < 9; ++k) acc[u] = fmaf(v[k], wp[k], acc[u]);
        }
    }
    int pixbase = y * 64 + x;
#pragma unroll
    for (int u = 0; u < 16; ++u) {
        int idx = (b * 64 + ocg * 16 + u) * 4096 + pixbase;
        float vm = ws[OFF_VM1 + idx];
        float sp = ws[OFF_S1 + idx];
        vm = vm * DECAY * (1.f - sp) + acc[u];
        ws[OFF_VM1 + idx] = vm;
        ws[OFF_S1 + idx] = (vm > 0.5f) ? 1.f : 0.f;
    }
}

// ---------------- maxpool 2x2 on s1 -> flat_all[t] (bf16, exact 0/1) ----------------
__global__ __launch_bounds__(256) void pool_pack(float* __restrict__ ws, int t) {
    int k = blockIdx.x * 256 + threadIdx.x;   // 0..65535 = c*1024 + y2*32 + x2
    int b = blockIdx.y;
    int c = k >> 10, r = (k >> 5) & 31, cc = k & 31;
    const float* s1 = ws + OFF_S1 + (((size_t)(b * 64 + c) * 64 + r * 2) * 64 + cc * 2);
    float m = fmaxf(fmaxf(s1[0], s1[1]), fmaxf(s1[64], s1[65]));
    unsigned short* flat = (unsigned short*)((char*)ws + OFF_FLAT_BYTES);
    flat[(size_t)(t * 16 + b) * 65536 + k] = (m > 0.5f) ? (unsigned short)0x3F80 : (unsigned short)0;
}

// ---------------- dense0 via bf16 MFMA, hi/lo weight split ----------------
// C[256][512] = flat[256][65536] @ D0^T.  grid (nb=8, kc=KSPLIT), block 256 (4 waves).
// M-tile = 256 (full M -> D0 read exactly once), N-tile 64, K-chunk 1024, k-tile 64.
// LDS pitch 72 halves (144 B row = 4-bank shift -> only 2-way conflicts = free).
__global__ __launch_bounds__(256) void dense0_mfma(const float* __restrict__ D0,
                                                   float* __restrict__ ws) {
    __shared__ unsigned short A_s[256 * 72];   // [m][k] bf16
    __shared__ unsigned short Bh_s[64 * 72];   // [n][k] bf16 hi
    __shared__ unsigned short Bl_s[64 * 72];   // [n][k] bf16 lo
    int tid = threadIdx.x;
    int nb = blockIdx.x, kc = blockIdx.y;
    int lane = tid & 63, w = tid >> 6, q = lane >> 4, r = lane & 15;
    const unsigned short* flat = (const unsigned short*)((const char*)ws + OFF_FLAT_BYTES);
    const size_t kbase = (size_t)kc * KCHUNK;

    floatx4 acc[4][4];
#pragma unroll
    for (int i = 0; i < 4; ++i)
#pragma unroll
        for (int j = 0; j < 4; ++j) acc[i][j] = (floatx4){0.f, 0.f, 0.f, 0.f};

    const unsigned short* aG = flat + (size_t)tid * 65536 + kbase;   // row tid, 8 vec8 per tile
    int bn = tid & 63, bks = (tid >> 6) * 16;                        // 4 threads/row, 16 k each
    const float* bG = D0 + (size_t)(nb * 64 + bn) * 65536 + kbase + bks;

    for (int k0 = 0; k0 < KCHUNK; k0 += 64) {
        // global loads for this k-tile
        uint4 av[8];
#pragma unroll
        for (int i = 0; i < 8; ++i) av[i] = *(const uint4*)(aG + k0 + i * 8);
        float4 bv[4];
#pragma unroll
        for (int j = 0; j < 4; ++j) bv[j] = *(const float4*)(bG + k0 + j * 4);

        __syncthreads();   // previous tile's LDS reads complete
#pragma unroll
        for (int i = 0; i < 8; ++i) *(uint4*)&A_s[tid * 72 + i * 8] = av[i];

        // hi/lo split of 16 weights
        float f[16];
#pragma unroll
        for (int j = 0; j < 4; ++j) { f[j*4+0]=bv[j].x; f[j*4+1]=bv[j].y; f[j*4+2]=bv[j].z; f[j*4+3]=bv[j].w; }
        unsigned hw[8], lw[8];
#pragma unroll
        for (int j = 0; j < 8; ++j) {
            unsigned short h0 = f2bf_rne(f[2*j]),   h1 = f2bf_rne(f[2*j+1]);
            unsigned short l0 = f2bf_rne(f[2*j]   - bf2f(h0));
            unsigned short l1 = f2bf_rne(f[2*j+1] - bf2f(h1));
            hw[j] = (unsigned)h0 | ((unsigned)h1 << 16);
            lw[j] = (unsigned)l0 | ((unsigned)l1 << 16);
        }
        *(uint4*)&Bh_s[bn * 72 + bks]     = make_uint4(hw[0], hw[1], hw[2], hw[3]);
        *(uint4*)&Bh_s[bn * 72 + bks + 8] = make_uint4(hw[4], hw[5], hw[6], hw[7]);
        *(uint4*)&Bl_s[bn * 72 + bks]     = make_uint4(lw[0], lw[1], lw[2], lw[3]);
        *(uint4*)&Bl_s[bn * 72 + bks + 8] = make_uint4(lw[4], lw[5], lw[6], lw[7]);
        __syncthreads();

#pragma unroll
        for (int ks = 0; ks < 64; ks += 32) {
            short8 af[4];
#pragma unroll
            for (int mi = 0; mi < 4; ++mi)
                af[mi] = *(const short8*)&A_s[(w * 64 + mi * 16 + r) * 72 + ks + q * 8];
#pragma unroll
            for (int ni = 0; ni < 4; ++ni) {
                short8 bh = *(const short8*)&Bh_s[(ni * 16 + r) * 72 + ks + q * 8];
                short8 bl = *(const short8*)&Bl_s[(ni * 16 + r) * 72 + ks + q * 8];
#pragma unroll
                for (int mi = 0; mi < 4; ++mi) {
                    acc[mi][ni] = __builtin_amdgcn_mfma_f32_16x16x32_bf16(af[mi], bh, acc[mi][ni], 0, 0, 0);
                    acc[mi][ni] = __builtin_amdgcn_mfma_f32_16x16x32_bf16(af[mi], bl, acc[mi][ni], 0, 0, 0);
                }
            }
        }
    }

    // C/D layout: n = lane&15, m = quad*4 + reg (verified m89/m91)
    float* part = (float*)((char*)ws + OFF_PART_BYTES);
#pragma unroll
    for (int mi = 0; mi < 4; ++mi)
#pragma unroll
        for (int ni = 0; ni < 4; ++ni) {
            int m0 = w * 64 + mi * 16 + q * 4;
            int n  = nb * 64 + ni * 16 + r;
#pragma unroll
            for (int rg = 0; rg < 4; ++rg)
                part[((size_t)kc * 256 + m0 + rg) * 512 + n] = acc[mi][ni][rg];
        }
}

// ---------------- reduce split-K partials: I[m][j] = sum_c part[c][m][j] ----------------
__global__ __launch_bounds__(256) void reduce_part(float* __restrict__ ws) {
    int e = blockIdx.x * 256 + threadIdx.x;    // 0..131071
    const float* part = (const float*)((const char*)ws + OFF_PART_BYTES);
    float s = 0.f;
#pragma unroll 8
    for (int c = 0; c < KSPLIT; ++c) s += part[(size_t)c * 131072 + e];
    ((float*)((char*)ws + OFF_I_BYTES))[e] = s;
}

// ---------------- tail: LIF2 + dense1 + LIF3 + acc over all t (single block) ----------------
__global__ __launch_bounds__(512) void tail_kernel(const float* __restrict__ D1,
                                                   float* __restrict__ out,
                                                   const float* __restrict__ ws_ro) {
    __shared__ float s2l[16][512];
    __shared__ float d1l[11 * 512];
    __shared__ float pb[2][176];
    int tid = threadIdx.x;
    for (int i = tid; i < 11 * 512; i += 512) d1l[i] = D1[i];
    const float* Ibuf = (const float*)((const char*)ws_ro + OFF_I_BYTES);

    float vm2[16];
#pragma unroll
    for (int i = 0; i < 16; ++i) vm2[i] = 0.f;
    unsigned s2mask = 0;
    float vm3 = 0.f, s3 = 0.f, accv = 0.f;
    int rb = tid / 11, ro = tid % 11;   // valid when tid < 176
    __syncthreads();

    for (int t = 0; t < TSTEPS; ++t) {
        // phase A: LIF2 — thread tid owns column j=tid for all 16 batches
        {
            int j = tid;
#pragma unroll
            for (int b = 0; b < 16; ++b) {
                float I = Ibuf[(size_t)(t * 16 + b) * 512 + j];
                float sp = ((s2mask >> b) & 1u) ? 1.f : 0.f;
                float vm = vm2[b] * DECAY * (1.f - sp) + I;
                vm2[b] = vm;
                unsigned sb = (vm > 0.5f) ? 1u : 0u;
                s2mask = (s2mask & ~(1u << b)) | (sb << b);
                s2l[b][j] = (float)sb;
            }
        }
        __syncthreads();
        // phase B: dense1 partials (2 k-halves x 176 outputs)
        if (tid < 352) {
            int g = tid / 176, rr = tid % 176;
            int b = rr / 11, o = rr % 11;
            float p = 0.f;
            int kbase = g * 256;
            for (int k = 0; k < 256; ++k)
                p = fmaf(s2l[b][kbase + k], d1l[o * 512 + kbase + k], p);
            pb[g][rr] = p;
        }
        __syncthreads();
        // phase C: LIF3 + acc
        if (tid < 176) {
            float I3 = pb[0][tid] + pb[1][tid];
            float vm = vm3 * DECAY * (1.f - s3) + I3;
            vm3 = vm;
            s3 = (vm > 0.5f) ? 1.f : 0.f;
            accv += s3;
        }
        __syncthreads();
    }
    if (tid < 176) out[rb * 11 + ro] = accv * (1.f / 16.f);
}

extern "C" void kernel_launch(void* const* d_in, const int* in_sizes, int n_in,
                              void* d_out, int out_size, void* d_ws, size_t ws_size,
                              hipStream_t stream) {
    (void)in_sizes; (void)n_in; (void)out_size; (void)ws_size;
    const float* in = (const float*)d_in[0];
    const float* W0 = (const float*)d_in[1];
    const float* W1 = (const float*)d_in[2];
    const float* D0 = (const float*)d_in[3];
    const float* D1 = (const float*)d_in[4];
    float* ws = (float*)d_ws;
    float* out = (float*)d_out;

    // zero the persistent LIF state (vm0,s0,vm1,s1) — ws is poisoned before every call
    hipMemsetAsync(d_ws, 0, ZERO_BYTES, stream);

    for (int t = 0; t < TSTEPS; ++t) {
        conv0_lif<<<dim3(16, 32, 16), 256, 0, stream>>>(in, W0, ws, t);
        conv1_lif<<<dim3(4, 16, 16), dim3(64, 4, 1), 0, stream>>>(W1, ws);
        pool_pack<<<dim3(256, 16), 256, 0, stream>>>(ws, t);
    }
    dense0_mfma<<<dim3(8, KSPLIT), 256, 0, stream>>>(D0, ws);
    reduce_part<<<512, 256, 0, stream>>>(ws);
    tail_kernel<<<1, 512, 0, stream>>>(D1, out, ws);
}